// Round 1
// baseline (257.692 us; speedup 1.0000x reference)
//
#include <hip/hip_runtime.h>

#define HID   100
#define GATES 400
#define INP   4
#define TMAX  256
#define SB    16      // sequences per block (one MFMA M-tile)
#define ULD   136     // u_lds row stride in halves (272 B, 16B-aligned, spreads banks)
#define NTH   512     // 8 waves

typedef _Float16 half8 __attribute__((ext_vector_type(8)));
typedef float    f32x4 __attribute__((ext_vector_type(4)));

__device__ __forceinline__ float fexp2(float x) { return __builtin_amdgcn_exp2f(x); }
__device__ __forceinline__ float frcp(float x)  { return __builtin_amdgcn_rcpf(x); }
__device__ __forceinline__ float sigm(float x)  { return frcp(1.f + fexp2(-1.44269504f * x)); }
// tanh(x) = 1 - 2/(exp2(2x*log2e)+1)
__device__ __forceinline__ float tanh_f(float x){ return 1.f - 2.f * frcp(1.f + fexp2(2.88539008f * x)); }

__global__ __launch_bounds__(NTH) void lstm_persist(
    const float* __restrict__ xg,     // [N][T][4]
    const float* __restrict__ w_ih,   // [400][4]
    const float* __restrict__ w_hh,   // [400][100]
    const float* __restrict__ b_ih,   // [400]
    const float* __restrict__ b_hh,   // [400]
    const int*   __restrict__ lens,   // [N]
    float* __restrict__ out)          // [N][100]
{
    __shared__ _Float16 u_lds[SB * ULD];      // [seq][136]: 0..99 h, 100..103 x, 104 = 1.0 (bias), rest 0
    __shared__ float    g_lds[SB * GATES];    // [seq][400] raw gates (incl. bias via k=104)
    __shared__ int      len_s[SB];
    __shared__ int      maxlen_s;

    const int tid  = threadIdx.x;
    const int wave = tid >> 6;
    const int lane = tid & 63;
    const int l15  = lane & 15;
    const int l4   = lane >> 4;
    const int seq0 = blockIdx.x * SB;

    if (tid < SB) len_s[tid] = lens[seq0 + tid];
    // zero u_lds; set bias column (k==104) to 1.0
    for (int i = tid; i < SB * ULD; i += NTH) {
        int col = i % ULD;
        u_lds[i] = (col == (HID + INP)) ? (_Float16)1.f : (_Float16)0.f;
    }

    // ---- B fragments (weights) resident in registers.
    // Wave w owns N-tiles w, w+8, w+16 (+24 for wave 0): 25 tiles total.
    // B[k][n] layout: lane holds col = l15 (gate), k = chunk*32 + l4*8 + j.
    half8 bfrag[4][4];
    int   tn[4];
    #pragma unroll
    for (int i = 0; i < 4; ++i) {
        int n = wave + 8 * i;
        tn[i] = n;
        if (n < 25) {
            int gate = n * 16 + l15;
            #pragma unroll
            for (int c = 0; c < 4; ++c) {
                half8 v;
                #pragma unroll
                for (int j = 0; j < 8; ++j) {
                    int k = c * 32 + l4 * 8 + j;
                    float w;
                    if (k < HID)             w = w_hh[gate * HID + k];
                    else if (k < HID + INP)  w = w_ih[gate * INP + (k - HID)];
                    else if (k == HID + INP) w = b_ih[gate] + b_hh[gate];
                    else                     w = 0.f;
                    v[j] = (_Float16)w;
                }
                bfrag[i][c] = v;
            }
        }
    }

    __syncthreads();
    if (tid == 0) {
        int m = 0;
        #pragma unroll
        for (int s = 0; s < SB; ++s) m = m > len_s[s] ? m : len_s[s];
        maxlen_s = m;
    }
    // x for t=0 (64 values: 16 seqs x 4)
    if (tid >= NTH - 64) {
        int idx = tid - (NTH - 64);
        int s = idx >> 2, c = idx & 3;
        u_lds[s * ULD + HID + c] = (_Float16)xg[(size_t)(seq0 + s) * TMAX * INP + c];
    }

    // ---- update-phase item assignment: 1600 items over 512 threads (3 + tid<64)
    int iseq[4], iunit[4], ilen[4];
    float creg[4] = {0.f, 0.f, 0.f, 0.f};
    #pragma unroll
    for (int ii = 0; ii < 4; ++ii) {
        int item = tid + NTH * ii;
        if (item < SB * HID) { iseq[ii] = item / HID; iunit[ii] = item % HID; }
        else                 { iseq[ii] = 0;          iunit[ii] = 0; }
    }
    __syncthreads();
    #pragma unroll
    for (int ii = 0; ii < 4; ++ii)
        ilen[ii] = (tid + NTH * ii < SB * HID) ? len_s[iseq[ii]] : 0;

    const int maxlen = maxlen_s;
    // A-frag base: row = l15 (seq), k = l4*8 (+chunk*32)
    const _Float16* abase = &u_lds[l15 * ULD + l4 * 8];

    for (int t = 0; t < maxlen; ++t) {
        // ---- MFMA phase: gates[16][400] = u[16][128] x W^T[128][400]
        half8 afr[4];
        #pragma unroll
        for (int c = 0; c < 4; ++c)
            afr[c] = *(const half8*)(abase + c * 32);
        #pragma unroll
        for (int i = 0; i < 4; ++i) {
            if (tn[i] < 25) {
                f32x4 acc = {0.f, 0.f, 0.f, 0.f};
                #pragma unroll
                for (int c = 0; c < 4; ++c)
                    acc = __builtin_amdgcn_mfma_f32_16x16x32_f16(afr[c], bfrag[i][c], acc, 0, 0, 0);
                // D: col(gate) = l15, row(seq) = l4*4 + r
                int gate = tn[i] * 16 + l15;
                #pragma unroll
                for (int r = 0; r < 4; ++r)
                    g_lds[(l4 * 4 + r) * GATES + gate] = acc[r];
            }
        }
        __syncthreads();

        // ---- x prefetch for t+1 (different u_lds region than h writes)
        if (tid >= NTH - 64 && t + 1 < maxlen) {
            int idx = tid - (NTH - 64);
            int s = idx >> 2, c = idx & 3;
            u_lds[s * ULD + HID + c] =
                (_Float16)xg[((size_t)(seq0 + s) * TMAX + (t + 1)) * INP + c];
        }

        // ---- elementwise update: c,h per (seq, unit), freeze at t >= len
        #pragma unroll
        for (int ii = 0; ii < 4; ++ii) {
            bool v = (ii < 3) || (tid < SB * HID - 3 * NTH);
            if (v && t < ilen[ii]) {
                const float* gp = &g_lds[iseq[ii] * GATES + iunit[ii]];
                float i_ = sigm(gp[0]);
                float f_ = sigm(gp[HID]);
                float g_ = tanh_f(gp[2 * HID]);
                float o_ = sigm(gp[3 * HID]);
                float cn = f_ * creg[ii] + i_ * g_;
                float hn = o_ * tanh_f(cn);
                creg[ii] = cn;
                u_lds[iseq[ii] * ULD + iunit[ii]] = (_Float16)hn;
                if (t == ilen[ii] - 1)
                    out[(size_t)(seq0 + iseq[ii]) * HID + iunit[ii]] = hn;
            }
        }
        __syncthreads();
    }
}

extern "C" void kernel_launch(void* const* d_in, const int* in_sizes, int n_in,
                              void* d_out, int out_size, void* d_ws, size_t ws_size,
                              hipStream_t stream) {
    const float* xg   = (const float*)d_in[0];
    const float* w_ih = (const float*)d_in[1];
    const float* w_hh = (const float*)d_in[2];
    const float* b_ih = (const float*)d_in[3];
    const float* b_hh = (const float*)d_in[4];
    const int*   lens = (const int*)d_in[5];
    float* out = (float*)d_out;
    const int N = in_sizes[5];           // 4096
    lstm_persist<<<dim3(N / SB), NTH, 0, stream>>>(xg, w_ih, w_hh, b_ih, b_hh, lens, out);
}